// Round 1
// baseline (444.775 us; speedup 1.0000x reference)
//
#include <hip/hip_runtime.h>

#define NORM_EPS 1e-12f
#define D 60
#define L 24

__device__ __forceinline__ float wave_sum(float v) {
    // full 64-lane butterfly; all lanes end with the total
    #pragma unroll
    for (int off = 32; off >= 1; off >>= 1)
        v += __shfl_xor(v, off, 64);
    return v;
}

__device__ __forceinline__ float word_pool(const float* __restrict__ word_emb,
                                           const int* __restrict__ ids,
                                           const int* __restrict__ mask,
                                           int b, int d, bool act)
{
    float acc = 0.f;
    int cnt = 0;
    #pragma unroll
    for (int l = 0; l < L; ++l) {
        int m = mask[b * L + l];      // wave-uniform
        if (m) {                      // uniform branch: skip masked-out gathers
            int id = ids[b * L + l];  // wave-uniform
            float v = act ? word_emb[(long)id * D + d] : 0.f;
            float ss = wave_sum(v * v);
            float n = sqrtf(ss);
            v = v / fmaxf(n, NORM_EPS);
            acc += v;
            cnt += 1;
        }
    }
    float c = (float)(cnt > 0 ? cnt : 1);
    return acc / c;
}

__global__ __launch_bounds__(256) void transe_score_kernel(
    const float* __restrict__ ent_emb,
    const float* __restrict__ rel_emb,
    const float* __restrict__ word_emb,
    const float* __restrict__ e_bias,
    const float* __restrict__ r_bias,
    const int* __restrict__ head,
    const int* __restrict__ relation,
    const int* __restrict__ tail,
    const int* __restrict__ head_w,
    const int* __restrict__ rel_w,
    const int* __restrict__ tail_w,
    const int* __restrict__ head_m,
    const int* __restrict__ rel_m,
    const int* __restrict__ tail_m,
    float* __restrict__ out,
    int B)
{
    int wid = (int)((blockIdx.x * (unsigned)blockDim.x + threadIdx.x) >> 6);
    int lane = (int)(threadIdx.x & 63u);
    if (wid >= B) return;

    int d = lane;
    bool act = d < D;

    int h = head[wid];
    int r = relation[wid];
    int t = tail[wid];

    // base rows, L2-normalized
    float vh = act ? ent_emb[(long)h * D + d] : 0.f;
    float vr = act ? rel_emb[(long)r * D + d] : 0.f;
    float vt = act ? ent_emb[(long)t * D + d] : 0.f;

    float nh = sqrtf(wave_sum(vh * vh));
    float nr = sqrtf(wave_sum(vr * vr));
    float nt = sqrtf(wave_sum(vt * vt));
    vh = vh / fmaxf(nh, NORM_EPS);
    vr = vr / fmaxf(nr, NORM_EPS);
    vt = vt / fmaxf(nt, NORM_EPS);

    // word pools (masked mean of per-row-normalized word embeddings)
    float ph = word_pool(word_emb, head_w, head_m, wid, d, act);
    float pr = word_pool(word_emb, rel_w,  rel_m,  wid, d, act);
    float pt = word_pool(word_emb, tail_w, tail_m, wid, d, act);

    float comb = (vh + ph) + (vr + pr) - (vt + pt);
    float nsc = sqrtf(wave_sum(comb * comb));

    float score = -nsc + e_bias[h] + e_bias[t] + r_bias[r];

    if (lane == 0) out[wid] = score;
}

extern "C" void kernel_launch(void* const* d_in, const int* in_sizes, int n_in,
                              void* d_out, int out_size, void* d_ws, size_t ws_size,
                              hipStream_t stream) {
    const float* ent_emb  = (const float*)d_in[0];
    const float* rel_emb  = (const float*)d_in[1];
    const float* word_emb = (const float*)d_in[2];
    const float* e_bias   = (const float*)d_in[3];
    const float* r_bias   = (const float*)d_in[4];
    const int*   head     = (const int*)d_in[5];
    const int*   relation = (const int*)d_in[6];
    const int*   tail     = (const int*)d_in[7];
    const int*   head_w   = (const int*)d_in[8];
    const int*   rel_w    = (const int*)d_in[9];
    const int*   tail_w   = (const int*)d_in[10];
    const int*   head_m   = (const int*)d_in[11];
    const int*   rel_m    = (const int*)d_in[12];
    const int*   tail_m   = (const int*)d_in[13];
    float* out = (float*)d_out;

    int B = in_sizes[5];

    // one wave (64 lanes) per batch item; 4 waves per 256-thread block
    int waves_per_block = 256 / 64;
    int grid = (B + waves_per_block - 1) / waves_per_block;
    transe_score_kernel<<<grid, 256, 0, stream>>>(
        ent_emb, rel_emb, word_emb, e_bias, r_bias,
        head, relation, tail,
        head_w, rel_w, tail_w,
        head_m, rel_m, tail_m,
        out, B);
}

// Round 2
// 431.696 us; speedup vs baseline: 1.0303x; 1.0303x over previous
//
#include <hip/hip_runtime.h>

#define NORM_EPS 1e-12f
#define D 60
#define L 24

__device__ __forceinline__ float wave_sum(float v) {
    #pragma unroll
    for (int off = 32; off >= 1; off >>= 1)
        v += __shfl_xor(v, off, 64);
    return v;
}

// ---------- precompute: inverse L2 norm per row of a [N, 60] table ----------
__global__ __launch_bounds__(256) void rownorm_kernel(
    const float* __restrict__ emb, float* __restrict__ invn, int N)
{
    int row = (int)((blockIdx.x * (unsigned)blockDim.x + threadIdx.x) >> 6);
    int lane = (int)(threadIdx.x & 63u);
    if (row >= N) return;
    float v = (lane < D) ? emb[(long)row * D + lane] : 0.f;
    float ss = wave_sum(v * v);
    if (lane == 0) invn[row] = 1.f / fmaxf(sqrtf(ss), NORM_EPS);
}

// ---------- main: wave per item, lane = dim; norms via precomputed invn ----------
__device__ __forceinline__ float word_pool_fast(const float* __restrict__ word_emb,
                                                const float* __restrict__ invn_word,
                                                const int* __restrict__ ids,
                                                const int* __restrict__ mask,
                                                int b, int d, bool act)
{
    float acc = 0.f;
    int cnt = 0;
    #pragma unroll
    for (int l = 0; l < L; ++l) {
        int m = mask[b * L + l];      // wave-uniform -> s_load + uniform branch
        if (m) {
            int id = ids[b * L + l];  // wave-uniform
            float w = invn_word[id];  // uniform broadcast load
            float v = act ? word_emb[(long)id * D + d] : 0.f;
            acc += v * w;
            cnt += 1;
        }
    }
    return acc / (float)(cnt > 0 ? cnt : 1);
}

__global__ __launch_bounds__(256) void transe_score_fast_kernel(
    const float* __restrict__ ent_emb,
    const float* __restrict__ rel_emb,
    const float* __restrict__ word_emb,
    const float* __restrict__ e_bias,
    const float* __restrict__ r_bias,
    const int* __restrict__ head,
    const int* __restrict__ relation,
    const int* __restrict__ tail,
    const int* __restrict__ head_w,
    const int* __restrict__ rel_w,
    const int* __restrict__ tail_w,
    const int* __restrict__ head_m,
    const int* __restrict__ rel_m,
    const int* __restrict__ tail_m,
    const float* __restrict__ invn_word,
    const float* __restrict__ invn_ent,
    const float* __restrict__ invn_rel,
    float* __restrict__ out,
    int B)
{
    int wid = (int)((blockIdx.x * (unsigned)blockDim.x + threadIdx.x) >> 6);
    int lane = (int)(threadIdx.x & 63u);
    if (wid >= B) return;

    int d = lane;
    bool act = d < D;

    int h = head[wid];
    int r = relation[wid];
    int t = tail[wid];

    float vh = (act ? ent_emb[(long)h * D + d] : 0.f) * invn_ent[h];
    float vr = (act ? rel_emb[(long)r * D + d] : 0.f) * invn_rel[r];
    float vt = (act ? ent_emb[(long)t * D + d] : 0.f) * invn_ent[t];

    float ph = word_pool_fast(word_emb, invn_word, head_w, head_m, wid, d, act);
    float pr = word_pool_fast(word_emb, invn_word, rel_w,  rel_m,  wid, d, act);
    float pt = word_pool_fast(word_emb, invn_word, tail_w, tail_m, wid, d, act);

    float comb = (vh + ph) + (vr + pr) - (vt + pt);
    float nsc = sqrtf(wave_sum(comb * comb));

    float score = -nsc + e_bias[h] + e_bias[t] + r_bias[r];
    if (lane == 0) out[wid] = score;
}

// ---------- fallback (round-0 verified kernel) if ws too small ----------
__device__ __forceinline__ float word_pool_slow(const float* __restrict__ word_emb,
                                                const int* __restrict__ ids,
                                                const int* __restrict__ mask,
                                                int b, int d, bool act)
{
    float acc = 0.f;
    int cnt = 0;
    #pragma unroll
    for (int l = 0; l < L; ++l) {
        int m = mask[b * L + l];
        if (m) {
            int id = ids[b * L + l];
            float v = act ? word_emb[(long)id * D + d] : 0.f;
            float n = sqrtf(wave_sum(v * v));
            acc += v / fmaxf(n, NORM_EPS);
            cnt += 1;
        }
    }
    return acc / (float)(cnt > 0 ? cnt : 1);
}

__global__ __launch_bounds__(256) void transe_score_slow_kernel(
    const float* __restrict__ ent_emb, const float* __restrict__ rel_emb,
    const float* __restrict__ word_emb, const float* __restrict__ e_bias,
    const float* __restrict__ r_bias,
    const int* __restrict__ head, const int* __restrict__ relation,
    const int* __restrict__ tail,
    const int* __restrict__ head_w, const int* __restrict__ rel_w,
    const int* __restrict__ tail_w,
    const int* __restrict__ head_m, const int* __restrict__ rel_m,
    const int* __restrict__ tail_m,
    float* __restrict__ out, int B)
{
    int wid = (int)((blockIdx.x * (unsigned)blockDim.x + threadIdx.x) >> 6);
    int lane = (int)(threadIdx.x & 63u);
    if (wid >= B) return;
    int d = lane;
    bool act = d < D;

    int h = head[wid], r = relation[wid], t = tail[wid];

    float vh = act ? ent_emb[(long)h * D + d] : 0.f;
    float vr = act ? rel_emb[(long)r * D + d] : 0.f;
    float vt = act ? ent_emb[(long)t * D + d] : 0.f;
    vh /= fmaxf(sqrtf(wave_sum(vh * vh)), NORM_EPS);
    vr /= fmaxf(sqrtf(wave_sum(vr * vr)), NORM_EPS);
    vt /= fmaxf(sqrtf(wave_sum(vt * vt)), NORM_EPS);

    float ph = word_pool_slow(word_emb, head_w, head_m, wid, d, act);
    float pr = word_pool_slow(word_emb, rel_w,  rel_m,  wid, d, act);
    float pt = word_pool_slow(word_emb, tail_w, tail_m, wid, d, act);

    float comb = (vh + ph) + (vr + pr) - (vt + pt);
    float nsc = sqrtf(wave_sum(comb * comb));
    float score = -nsc + e_bias[h] + e_bias[t] + r_bias[r];
    if (lane == 0) out[wid] = score;
}

extern "C" void kernel_launch(void* const* d_in, const int* in_sizes, int n_in,
                              void* d_out, int out_size, void* d_ws, size_t ws_size,
                              hipStream_t stream) {
    const float* ent_emb  = (const float*)d_in[0];
    const float* rel_emb  = (const float*)d_in[1];
    const float* word_emb = (const float*)d_in[2];
    const float* e_bias   = (const float*)d_in[3];
    const float* r_bias   = (const float*)d_in[4];
    const int*   head     = (const int*)d_in[5];
    const int*   relation = (const int*)d_in[6];
    const int*   tail     = (const int*)d_in[7];
    const int*   head_w   = (const int*)d_in[8];
    const int*   rel_w    = (const int*)d_in[9];
    const int*   tail_w   = (const int*)d_in[10];
    const int*   head_m   = (const int*)d_in[11];
    const int*   rel_m    = (const int*)d_in[12];
    const int*   tail_m   = (const int*)d_in[13];
    float* out = (float*)d_out;

    int B  = in_sizes[5];
    int NE = in_sizes[0] / D;   // 500000
    int NR = in_sizes[1] / D;   // 1000
    int NW = in_sizes[2] / D;   // 100000

    size_t need = (size_t)(NE + NR + NW) * sizeof(float);
    int waves_per_block = 256 / 64;

    if (ws_size >= need) {
        float* invn_word = (float*)d_ws;
        float* invn_ent  = invn_word + NW;
        float* invn_rel  = invn_ent + NE;

        rownorm_kernel<<<(NW + waves_per_block - 1) / waves_per_block, 256, 0, stream>>>(
            word_emb, invn_word, NW);
        rownorm_kernel<<<(NE + waves_per_block - 1) / waves_per_block, 256, 0, stream>>>(
            ent_emb, invn_ent, NE);
        rownorm_kernel<<<(NR + waves_per_block - 1) / waves_per_block, 256, 0, stream>>>(
            rel_emb, invn_rel, NR);

        transe_score_fast_kernel<<<(B + waves_per_block - 1) / waves_per_block, 256, 0, stream>>>(
            ent_emb, rel_emb, word_emb, e_bias, r_bias,
            head, relation, tail,
            head_w, rel_w, tail_w,
            head_m, rel_m, tail_m,
            invn_word, invn_ent, invn_rel,
            out, B);
    } else {
        transe_score_slow_kernel<<<(B + waves_per_block - 1) / waves_per_block, 256, 0, stream>>>(
            ent_emb, rel_emb, word_emb, e_bias, r_bias,
            head, relation, tail,
            head_w, rel_w, tail_w,
            head_m, rel_m, tail_m,
            out, B);
    }
}

// Round 3
// 296.718 us; speedup vs baseline: 1.4990x; 1.4549x over previous
//
#include <hip/hip_runtime.h>

#define NORM_EPS 1e-12f
#define D 60
#define L 24

__device__ __forceinline__ float wave_sum(float v) {
    #pragma unroll
    for (int off = 32; off >= 1; off >>= 1)
        v += __shfl_xor(v, off, 64);
    return v;
}

// ---------- precompute: inverse L2 norm per row ----------
__global__ __launch_bounds__(256) void rownorm_kernel(
    const float* __restrict__ emb, float* __restrict__ invn, int N)
{
    int row = (int)((blockIdx.x * (unsigned)blockDim.x + threadIdx.x) >> 6);
    int lane = (int)(threadIdx.x & 63u);
    if (row >= N) return;
    float v = (lane < D) ? emb[(long)row * D + lane] : 0.f;
    float ss = wave_sum(v * v);
    if (lane == 0) invn[row] = 1.f / fmaxf(sqrtf(ss), NORM_EPS);
}

// ---------- precompute: normalized word table ----------
__global__ __launch_bounds__(256) void word_norm_kernel(
    const float* __restrict__ emb, float* __restrict__ outw, int N)
{
    int row = (int)((blockIdx.x * (unsigned)blockDim.x + threadIdx.x) >> 6);
    int lane = (int)(threadIdx.x & 63u);
    if (row >= N) return;
    float v = (lane < D) ? emb[(long)row * D + lane] : 0.f;
    float ss = wave_sum(v * v);
    float inv = 1.f / fmaxf(sqrtf(ss), NORM_EPS);
    if (lane < D) outw[(long)row * D + lane] = v * inv;
}

// ---------- branch-free pooled gather from pre-normalized table ----------
__device__ __forceinline__ float word_pool_norm(const float* __restrict__ wn,
                                                const int* __restrict__ ids,
                                                const int* __restrict__ mask,
                                                int b, int d, bool act)
{
    const int4* idv = (const int4*)(ids + (long)b * L);
    const int4* mv  = (const int4*)(mask + (long)b * L);
    int id[L], m[L];
    #pragma unroll
    for (int i = 0; i < L / 4; ++i) {
        int4 ti = idv[i];
        int4 tm = mv[i];
        id[4*i+0] = ti.x; id[4*i+1] = ti.y; id[4*i+2] = ti.z; id[4*i+3] = ti.w;
        m[4*i+0]  = tm.x; m[4*i+1]  = tm.y; m[4*i+2]  = tm.z; m[4*i+3]  = tm.w;
    }
    float v[L];
    #pragma unroll
    for (int l = 0; l < L; ++l) {
        int sid = m[l] ? id[l] : 0;           // masked -> row 0 (L1-resident)
        v[l] = act ? wn[(long)sid * D + d] : 0.f;
    }
    float acc = 0.f;
    int cnt = 0;
    #pragma unroll
    for (int l = 0; l < L; ++l) {
        acc += m[l] ? v[l] : 0.f;
        cnt += m[l];
    }
    return acc / (float)(cnt > 0 ? cnt : 1);
}

// ---------- branch-free pooled gather with separate invn table ----------
__device__ __forceinline__ float word_pool_invn(const float* __restrict__ we,
                                                const float* __restrict__ invn,
                                                const int* __restrict__ ids,
                                                const int* __restrict__ mask,
                                                int b, int d, bool act)
{
    const int4* idv = (const int4*)(ids + (long)b * L);
    const int4* mv  = (const int4*)(mask + (long)b * L);
    int id[L], m[L];
    #pragma unroll
    for (int i = 0; i < L / 4; ++i) {
        int4 ti = idv[i];
        int4 tm = mv[i];
        id[4*i+0] = ti.x; id[4*i+1] = ti.y; id[4*i+2] = ti.z; id[4*i+3] = ti.w;
        m[4*i+0]  = tm.x; m[4*i+1]  = tm.y; m[4*i+2]  = tm.z; m[4*i+3]  = tm.w;
    }
    float v[L], w[L];
    #pragma unroll
    for (int l = 0; l < L; ++l) {
        int sid = m[l] ? id[l] : 0;
        v[l] = act ? we[(long)sid * D + d] : 0.f;
        w[l] = invn[sid];
    }
    float acc = 0.f;
    int cnt = 0;
    #pragma unroll
    for (int l = 0; l < L; ++l) {
        acc += m[l] ? v[l] * w[l] : 0.f;
        cnt += m[l];
    }
    return acc / (float)(cnt > 0 ? cnt : 1);
}

template <int MODE>  // 1 = word_norm table, 2 = invn tables
__global__ __launch_bounds__(256) void transe_score_kernel_t(
    const float* __restrict__ ent_emb,
    const float* __restrict__ rel_emb,
    const float* __restrict__ word_emb,
    const float* __restrict__ e_bias,
    const float* __restrict__ r_bias,
    const int* __restrict__ head,
    const int* __restrict__ relation,
    const int* __restrict__ tail,
    const int* __restrict__ head_w,
    const int* __restrict__ rel_w,
    const int* __restrict__ tail_w,
    const int* __restrict__ head_m,
    const int* __restrict__ rel_m,
    const int* __restrict__ tail_m,
    const float* __restrict__ word_tab,   // MODE1: normalized word table; MODE2: raw word_emb
    const float* __restrict__ invn_word,  // MODE2 only
    const float* __restrict__ invn_ent,
    const float* __restrict__ invn_rel,
    float* __restrict__ out,
    int B)
{
    int wid = (int)((blockIdx.x * (unsigned)blockDim.x + threadIdx.x) >> 6);
    int lane = (int)(threadIdx.x & 63u);
    if (wid >= B) return;

    int d = lane;
    bool act = d < D;

    int h = head[wid];
    int r = relation[wid];
    int t = tail[wid];

    float vh = (act ? ent_emb[(long)h * D + d] : 0.f) * invn_ent[h];
    float vr = (act ? rel_emb[(long)r * D + d] : 0.f) * invn_rel[r];
    float vt = (act ? ent_emb[(long)t * D + d] : 0.f) * invn_ent[t];

    float ph, pr, pt;
    if (MODE == 1) {
        ph = word_pool_norm(word_tab, head_w, head_m, wid, d, act);
        pr = word_pool_norm(word_tab, rel_w,  rel_m,  wid, d, act);
        pt = word_pool_norm(word_tab, tail_w, tail_m, wid, d, act);
    } else {
        ph = word_pool_invn(word_tab, invn_word, head_w, head_m, wid, d, act);
        pr = word_pool_invn(word_tab, invn_word, rel_w,  rel_m,  wid, d, act);
        pt = word_pool_invn(word_tab, invn_word, tail_w, tail_m, wid, d, act);
    }

    float comb = (vh + ph) + (vr + pr) - (vt + pt);
    float nsc = sqrtf(wave_sum(comb * comb));

    float score = -nsc + e_bias[h] + e_bias[t] + r_bias[r];
    if (lane == 0) out[wid] = score;
}

// ---------- slow fallback (round-0 verified) ----------
__device__ __forceinline__ float word_pool_slow(const float* __restrict__ word_emb,
                                                const int* __restrict__ ids,
                                                const int* __restrict__ mask,
                                                int b, int d, bool act)
{
    float acc = 0.f;
    int cnt = 0;
    #pragma unroll
    for (int l = 0; l < L; ++l) {
        int m = mask[b * L + l];
        if (m) {
            int id = ids[b * L + l];
            float v = act ? word_emb[(long)id * D + d] : 0.f;
            float n = sqrtf(wave_sum(v * v));
            acc += v / fmaxf(n, NORM_EPS);
            cnt += 1;
        }
    }
    return acc / (float)(cnt > 0 ? cnt : 1);
}

__global__ __launch_bounds__(256) void transe_score_slow_kernel(
    const float* __restrict__ ent_emb, const float* __restrict__ rel_emb,
    const float* __restrict__ word_emb, const float* __restrict__ e_bias,
    const float* __restrict__ r_bias,
    const int* __restrict__ head, const int* __restrict__ relation,
    const int* __restrict__ tail,
    const int* __restrict__ head_w, const int* __restrict__ rel_w,
    const int* __restrict__ tail_w,
    const int* __restrict__ head_m, const int* __restrict__ rel_m,
    const int* __restrict__ tail_m,
    float* __restrict__ out, int B)
{
    int wid = (int)((blockIdx.x * (unsigned)blockDim.x + threadIdx.x) >> 6);
    int lane = (int)(threadIdx.x & 63u);
    if (wid >= B) return;
    int d = lane;
    bool act = d < D;

    int h = head[wid], r = relation[wid], t = tail[wid];

    float vh = act ? ent_emb[(long)h * D + d] : 0.f;
    float vr = act ? rel_emb[(long)r * D + d] : 0.f;
    float vt = act ? ent_emb[(long)t * D + d] : 0.f;
    vh /= fmaxf(sqrtf(wave_sum(vh * vh)), NORM_EPS);
    vr /= fmaxf(sqrtf(wave_sum(vr * vr)), NORM_EPS);
    vt /= fmaxf(sqrtf(wave_sum(vt * vt)), NORM_EPS);

    float ph = word_pool_slow(word_emb, head_w, head_m, wid, d, act);
    float pr = word_pool_slow(word_emb, rel_w,  rel_m,  wid, d, act);
    float pt = word_pool_slow(word_emb, tail_w, tail_m, wid, d, act);

    float comb = (vh + ph) + (vr + pr) - (vt + pt);
    float nsc = sqrtf(wave_sum(comb * comb));
    float score = -nsc + e_bias[h] + e_bias[t] + r_bias[r];
    if (lane == 0) out[wid] = score;
}

extern "C" void kernel_launch(void* const* d_in, const int* in_sizes, int n_in,
                              void* d_out, int out_size, void* d_ws, size_t ws_size,
                              hipStream_t stream) {
    const float* ent_emb  = (const float*)d_in[0];
    const float* rel_emb  = (const float*)d_in[1];
    const float* word_emb = (const float*)d_in[2];
    const float* e_bias   = (const float*)d_in[3];
    const float* r_bias   = (const float*)d_in[4];
    const int*   head     = (const int*)d_in[5];
    const int*   relation = (const int*)d_in[6];
    const int*   tail     = (const int*)d_in[7];
    const int*   head_w   = (const int*)d_in[8];
    const int*   rel_w    = (const int*)d_in[9];
    const int*   tail_w   = (const int*)d_in[10];
    const int*   head_m   = (const int*)d_in[11];
    const int*   rel_m    = (const int*)d_in[12];
    const int*   tail_m   = (const int*)d_in[13];
    float* out = (float*)d_out;

    int B  = in_sizes[5];
    int NE = in_sizes[0] / D;   // 500000
    int NR = in_sizes[1] / D;   // 1000
    int NW = in_sizes[2] / D;   // 100000

    int wpb = 256 / 64;  // waves per block

    size_t need_norms = (size_t)(NE + NR) * sizeof(float);
    size_t need_tab   = (size_t)NW * D * sizeof(float);
    size_t need_invw  = (size_t)NW * sizeof(float);

    if (ws_size >= need_tab + need_norms) {
        // tier 1: normalized word table + ent/rel inv norms
        float* word_norm = (float*)d_ws;
        float* invn_ent  = word_norm + (size_t)NW * D;
        float* invn_rel  = invn_ent + NE;

        word_norm_kernel<<<(NW + wpb - 1) / wpb, 256, 0, stream>>>(word_emb, word_norm, NW);
        rownorm_kernel<<<(NE + wpb - 1) / wpb, 256, 0, stream>>>(ent_emb, invn_ent, NE);
        rownorm_kernel<<<(NR + wpb - 1) / wpb, 256, 0, stream>>>(rel_emb, invn_rel, NR);

        transe_score_kernel_t<1><<<(B + wpb - 1) / wpb, 256, 0, stream>>>(
            ent_emb, rel_emb, word_emb, e_bias, r_bias,
            head, relation, tail,
            head_w, rel_w, tail_w, head_m, rel_m, tail_m,
            word_norm, (const float*)nullptr, invn_ent, invn_rel, out, B);
    } else if (ws_size >= need_invw + need_norms) {
        // tier 2: inv norms for all tables, branch-free gathers
        float* invn_word = (float*)d_ws;
        float* invn_ent  = invn_word + NW;
        float* invn_rel  = invn_ent + NE;

        rownorm_kernel<<<(NW + wpb - 1) / wpb, 256, 0, stream>>>(word_emb, invn_word, NW);
        rownorm_kernel<<<(NE + wpb - 1) / wpb, 256, 0, stream>>>(ent_emb, invn_ent, NE);
        rownorm_kernel<<<(NR + wpb - 1) / wpb, 256, 0, stream>>>(rel_emb, invn_rel, NR);

        transe_score_kernel_t<2><<<(B + wpb - 1) / wpb, 256, 0, stream>>>(
            ent_emb, rel_emb, word_emb, e_bias, r_bias,
            head, relation, tail,
            head_w, rel_w, tail_w, head_m, rel_m, tail_m,
            word_emb, invn_word, invn_ent, invn_rel, out, B);
    } else {
        transe_score_slow_kernel<<<(B + wpb - 1) / wpb, 256, 0, stream>>>(
            ent_emb, rel_emb, word_emb, e_bias, r_bias,
            head, relation, tail,
            head_w, rel_w, tail_w, head_m, rel_m, tail_m, out, B);
    }
}

// Round 4
// 186.898 us; speedup vs baseline: 2.3798x; 1.5876x over previous
//
#include <hip/hip_runtime.h>
#include <hip/hip_bf16.h>

#define NORM_EPS 1e-12f
#define D 60
#define RP 64   // padded row length (elements) -> 128 B rows, line-aligned
#define L 24

__device__ __forceinline__ float wave_sum(float v) {
    #pragma unroll
    for (int off = 32; off >= 1; off >>= 1)
        v += __shfl_xor(v, off, 64);
    return v;
}

__device__ __forceinline__ int rfl(int x) { return __builtin_amdgcn_readfirstlane(x); }

// ---------- precompute: L2-normalized bf16 table, rows padded to RP ----------
__global__ __launch_bounds__(256) void norm_bf16_kernel(
    const float* __restrict__ emb, __hip_bfloat16* __restrict__ outw, int N)
{
    int row = (int)((blockIdx.x * (unsigned)blockDim.x + threadIdx.x) >> 6);
    int lane = (int)(threadIdx.x & 63u);
    if (row >= N) return;
    float v = (lane < D) ? emb[(size_t)row * D + lane] : 0.f;
    float ss = wave_sum(v * v);
    float inv = 1.f / fmaxf(sqrtf(ss), NORM_EPS);
    if (lane < D) outw[(size_t)row * RP + lane] = __float2bfloat16(v * inv);
}

// ---------- precompute: inverse L2 norm per row (tier-B) ----------
__global__ __launch_bounds__(256) void rownorm_kernel(
    const float* __restrict__ emb, float* __restrict__ invn, int N)
{
    int row = (int)((blockIdx.x * (unsigned)blockDim.x + threadIdx.x) >> 6);
    int lane = (int)(threadIdx.x & 63u);
    if (row >= N) return;
    float v = (lane < D) ? emb[(size_t)row * D + lane] : 0.f;
    float ss = wave_sum(v * v);
    if (lane == 0) invn[row] = 1.f / fmaxf(sqrtf(ss), NORM_EPS);
}

// ---------- pooled gather from bf16 normalized table, scalar ids ----------
__device__ __forceinline__ float pool_bf16(const __hip_bfloat16* __restrict__ wt,
                                           const int* __restrict__ ids,
                                           const int* __restrict__ mask,
                                           int b, int doff)
{
    const int4* ip = (const int4*)(ids + (size_t)b * L);
    const int4* mp = (const int4*)(mask + (size_t)b * L);
    int id[L], m[L];
    #pragma unroll
    for (int i = 0; i < L / 4; ++i) {
        int4 ti = ip[i];
        id[4*i+0] = rfl(ti.x); id[4*i+1] = rfl(ti.y);
        id[4*i+2] = rfl(ti.z); id[4*i+3] = rfl(ti.w);
        int4 tm = mp[i];
        m[4*i+0] = rfl(tm.x); m[4*i+1] = rfl(tm.y);
        m[4*i+2] = rfl(tm.z); m[4*i+3] = rfl(tm.w);
    }
    int cnt = 0;
    #pragma unroll
    for (int l = 0; l < L; ++l) cnt += (m[l] ? 1 : 0);

    // unconditional gathers; masked slots read row 0 (L1-hot), corrected below
    float v[L];
    #pragma unroll
    for (int l = 0; l < L; ++l) {
        int sid = m[l] ? id[l] : 0;          // scalar select (SALU)
        v[l] = __bfloat162float(wt[(size_t)sid * RP + doff]);
    }
    float s0 = 0.f, s1 = 0.f, s2 = 0.f, s3 = 0.f;
    #pragma unroll
    for (int l = 0; l < L; l += 4) {
        s0 += v[l]; s1 += v[l+1]; s2 += v[l+2]; s3 += v[l+3];
    }
    float acc = (s0 + s1) + (s2 + s3);
    float v0 = __bfloat162float(wt[doff]);
    acc -= (float)(L - cnt) * v0;            // exact: masked slots loaded row 0
    return acc / (float)(cnt > 0 ? cnt : 1);
}

// MODE 0: ent/rel from bf16 padded tables; MODE 1: ent/rel f32 gathers * invn
template <int MODE>
__global__ __launch_bounds__(256) void score_kernel_t(
    const __hip_bfloat16* __restrict__ wt,   // normalized word table [NW*RP]
    const __hip_bfloat16* __restrict__ et,   // MODE0: normalized ent table
    const __hip_bfloat16* __restrict__ rt,   // MODE0: normalized rel table
    const float* __restrict__ ent_emb,       // MODE1
    const float* __restrict__ rel_emb,       // MODE1
    const float* __restrict__ invn_ent,      // MODE1
    const float* __restrict__ invn_rel,      // MODE1
    const float* __restrict__ e_bias,
    const float* __restrict__ r_bias,
    const int* __restrict__ head,
    const int* __restrict__ relation,
    const int* __restrict__ tail,
    const int* __restrict__ head_w,
    const int* __restrict__ rel_w,
    const int* __restrict__ tail_w,
    const int* __restrict__ head_m,
    const int* __restrict__ rel_m,
    const int* __restrict__ tail_m,
    float* __restrict__ out,
    int B)
{
    int wid = (int)((blockIdx.x * (unsigned)blockDim.x + threadIdx.x) >> 6);
    int lane = (int)(threadIdx.x & 63u);
    if (wid >= B) return;
    int b = rfl(wid);

    int d = lane;
    int doff = (d < D) ? d : 0;   // inactive lanes read dim 0; zeroed before reduce

    int h = rfl(head[b]);
    int r = rfl(relation[b]);
    int t = rfl(tail[b]);

    float vh, vr, vt;
    if (MODE == 0) {
        vh = __bfloat162float(et[(size_t)h * RP + doff]);
        vr = __bfloat162float(rt[(size_t)r * RP + doff]);
        vt = __bfloat162float(et[(size_t)t * RP + doff]);
    } else {
        vh = ent_emb[(size_t)h * D + doff] * invn_ent[h];
        vr = rel_emb[(size_t)r * D + doff] * invn_rel[r];
        vt = ent_emb[(size_t)t * D + doff] * invn_ent[t];
    }

    float ph = pool_bf16(wt, head_w, head_m, b, doff);
    float pr = pool_bf16(wt, rel_w,  rel_m,  b, doff);
    float pt = pool_bf16(wt, tail_w, tail_m, b, doff);

    float comb = (vh + ph) + (vr + pr) - (vt + pt);
    comb = (d < D) ? comb : 0.f;
    float nsc = sqrtf(wave_sum(comb * comb));

    float score = -nsc + e_bias[h] + e_bias[t] + r_bias[r];
    if (lane == 0) out[wid] = score;
}

// ---------- slow fallback (round-0 verified; used only if ws too small) ----------
__device__ __forceinline__ float word_pool_slow(const float* __restrict__ word_emb,
                                                const int* __restrict__ ids,
                                                const int* __restrict__ mask,
                                                int b, int d, bool act)
{
    float acc = 0.f;
    int cnt = 0;
    #pragma unroll
    for (int l = 0; l < L; ++l) {
        int m = mask[b * L + l];
        if (m) {
            int id = ids[b * L + l];
            float v = act ? word_emb[(size_t)id * D + d] : 0.f;
            float n = sqrtf(wave_sum(v * v));
            acc += v / fmaxf(n, NORM_EPS);
            cnt += 1;
        }
    }
    return acc / (float)(cnt > 0 ? cnt : 1);
}

__global__ __launch_bounds__(256) void transe_score_slow_kernel(
    const float* __restrict__ ent_emb, const float* __restrict__ rel_emb,
    const float* __restrict__ word_emb, const float* __restrict__ e_bias,
    const float* __restrict__ r_bias,
    const int* __restrict__ head, const int* __restrict__ relation,
    const int* __restrict__ tail,
    const int* __restrict__ head_w, const int* __restrict__ rel_w,
    const int* __restrict__ tail_w,
    const int* __restrict__ head_m, const int* __restrict__ rel_m,
    const int* __restrict__ tail_m,
    float* __restrict__ out, int B)
{
    int wid = (int)((blockIdx.x * (unsigned)blockDim.x + threadIdx.x) >> 6);
    int lane = (int)(threadIdx.x & 63u);
    if (wid >= B) return;
    int d = lane;
    bool act = d < D;

    int h = head[wid], r = relation[wid], t = tail[wid];

    float vh = act ? ent_emb[(size_t)h * D + d] : 0.f;
    float vr = act ? rel_emb[(size_t)r * D + d] : 0.f;
    float vt = act ? ent_emb[(size_t)t * D + d] : 0.f;
    vh /= fmaxf(sqrtf(wave_sum(vh * vh)), NORM_EPS);
    vr /= fmaxf(sqrtf(wave_sum(vr * vr)), NORM_EPS);
    vt /= fmaxf(sqrtf(wave_sum(vt * vt)), NORM_EPS);

    float ph = word_pool_slow(word_emb, head_w, head_m, wid, d, act);
    float pr = word_pool_slow(word_emb, rel_w,  rel_m,  wid, d, act);
    float pt = word_pool_slow(word_emb, tail_w, tail_m, wid, d, act);

    float comb = (vh + ph) + (vr + pr) - (vt + pt);
    float nsc = sqrtf(wave_sum(comb * comb));
    float score = -nsc + e_bias[h] + e_bias[t] + r_bias[r];
    if (lane == 0) out[wid] = score;
}

extern "C" void kernel_launch(void* const* d_in, const int* in_sizes, int n_in,
                              void* d_out, int out_size, void* d_ws, size_t ws_size,
                              hipStream_t stream) {
    const float* ent_emb  = (const float*)d_in[0];
    const float* rel_emb  = (const float*)d_in[1];
    const float* word_emb = (const float*)d_in[2];
    const float* e_bias   = (const float*)d_in[3];
    const float* r_bias   = (const float*)d_in[4];
    const int*   head     = (const int*)d_in[5];
    const int*   relation = (const int*)d_in[6];
    const int*   tail     = (const int*)d_in[7];
    const int*   head_w   = (const int*)d_in[8];
    const int*   rel_w    = (const int*)d_in[9];
    const int*   tail_w   = (const int*)d_in[10];
    const int*   head_m   = (const int*)d_in[11];
    const int*   rel_m    = (const int*)d_in[12];
    const int*   tail_m   = (const int*)d_in[13];
    float* out = (float*)d_out;

    int B  = in_sizes[5];
    int NE = in_sizes[0] / D;   // 500000
    int NR = in_sizes[1] / D;   // 1000
    int NW = in_sizes[2] / D;   // 100000

    int wpb = 256 / 64;  // waves per block

    size_t need_A = (size_t)(NW + NE + NR) * RP * sizeof(__hip_bfloat16);        // ~77 MB
    size_t need_B = (size_t)NW * RP * sizeof(__hip_bfloat16)
                  + (size_t)(NE + NR) * sizeof(float);                            // ~14.8 MB

    if (ws_size >= need_A) {
        __hip_bfloat16* wt = (__hip_bfloat16*)d_ws;
        __hip_bfloat16* et = wt + (size_t)NW * RP;
        __hip_bfloat16* rt = et + (size_t)NE * RP;

        norm_bf16_kernel<<<(NW + wpb - 1) / wpb, 256, 0, stream>>>(word_emb, wt, NW);
        norm_bf16_kernel<<<(NE + wpb - 1) / wpb, 256, 0, stream>>>(ent_emb, et, NE);
        norm_bf16_kernel<<<(NR + wpb - 1) / wpb, 256, 0, stream>>>(rel_emb, rt, NR);

        score_kernel_t<0><<<(B + wpb - 1) / wpb, 256, 0, stream>>>(
            wt, et, rt,
            (const float*)nullptr, (const float*)nullptr,
            (const float*)nullptr, (const float*)nullptr,
            e_bias, r_bias, head, relation, tail,
            head_w, rel_w, tail_w, head_m, rel_m, tail_m, out, B);
    } else if (ws_size >= need_B) {
        __hip_bfloat16* wt = (__hip_bfloat16*)d_ws;
        float* invn_ent = (float*)(wt + (size_t)NW * RP);
        float* invn_rel = invn_ent + NE;

        norm_bf16_kernel<<<(NW + wpb - 1) / wpb, 256, 0, stream>>>(word_emb, wt, NW);
        rownorm_kernel<<<(NE + wpb - 1) / wpb, 256, 0, stream>>>(ent_emb, invn_ent, NE);
        rownorm_kernel<<<(NR + wpb - 1) / wpb, 256, 0, stream>>>(rel_emb, invn_rel, NR);

        score_kernel_t<1><<<(B + wpb - 1) / wpb, 256, 0, stream>>>(
            wt, (const __hip_bfloat16*)nullptr, (const __hip_bfloat16*)nullptr,
            ent_emb, rel_emb, invn_ent, invn_rel,
            e_bias, r_bias, head, relation, tail,
            head_w, rel_w, tail_w, head_m, rel_m, tail_m, out, B);
    } else {
        transe_score_slow_kernel<<<(B + wpb - 1) / wpb, 256, 0, stream>>>(
            ent_emb, rel_emb, word_emb, e_bias, r_bias,
            head, relation, tail,
            head_w, rel_w, tail_w, head_m, rel_m, tail_m, out, B);
    }
}

// Round 5
// 148.692 us; speedup vs baseline: 2.9912x; 1.2569x over previous
//
#include <hip/hip_runtime.h>
#include <hip/hip_bf16.h>

#define NORM_EPS 1e-12f
#define D 60
#define RP 64   // padded row length (elements) -> 128 B rows, line-aligned
#define L 24

__device__ __forceinline__ float wave_sum(float v) {
    #pragma unroll
    for (int off = 32; off >= 1; off >>= 1)
        v += __shfl_xor(v, off, 64);
    return v;
}

__device__ __forceinline__ int rfl(int x) { return __builtin_amdgcn_readfirstlane(x); }

__device__ __forceinline__ unsigned pack_bf16(float a, float b) {
    __hip_bfloat16 lo = __float2bfloat16(a);   // RNE
    __hip_bfloat16 hi = __float2bfloat16(b);
    unsigned short ul, uh;
    __builtin_memcpy(&ul, &lo, 2);
    __builtin_memcpy(&uh, &hi, 2);
    return (unsigned)ul | ((unsigned)uh << 16);
}

// ---------- precompute: L2-normalized bf16 table, thread-per-row, no cross-lane ----------
__global__ __launch_bounds__(256) void norm_bf16_fast_kernel(
    const float* __restrict__ emb, __hip_bfloat16* __restrict__ outw, int N)
{
    int row = (int)(blockIdx.x * blockDim.x + threadIdx.x);
    if (row >= N) return;

    const float4* src = (const float4*)(emb + (size_t)row * D);  // 240 B rows, 16B-aligned
    float4 v[15];
    #pragma unroll
    for (int i = 0; i < 15; ++i) v[i] = src[i];

    float ss = 0.f;
    #pragma unroll
    for (int i = 0; i < 15; ++i)
        ss += v[i].x * v[i].x + v[i].y * v[i].y + v[i].z * v[i].z + v[i].w * v[i].w;
    float inv = 1.f / fmaxf(sqrtf(ss), NORM_EPS);

    // pack 60 bf16 + 4 zero pad into 8 x uint4 (128 B)
    float f[60];
    #pragma unroll
    for (int i = 0; i < 15; ++i) {
        f[4*i+0] = v[i].x * inv; f[4*i+1] = v[i].y * inv;
        f[4*i+2] = v[i].z * inv; f[4*i+3] = v[i].w * inv;
    }
    unsigned w[32];
    #pragma unroll
    for (int i = 0; i < 30; ++i) w[i] = pack_bf16(f[2*i], f[2*i+1]);
    w[30] = 0u; w[31] = 0u;

    uint4* dst = (uint4*)(outw + (size_t)row * RP);  // 128 B rows, 16B-aligned
    #pragma unroll
    for (int j = 0; j < 8; ++j)
        dst[j] = make_uint4(w[4*j+0], w[4*j+1], w[4*j+2], w[4*j+3]);
}

// ---------- pooled gather from bf16 normalized table, scalar ids ----------
__device__ __forceinline__ float pool_bf16(const __hip_bfloat16* __restrict__ wt,
                                           const int* __restrict__ ids,
                                           const int* __restrict__ mask,
                                           int b, int doff)
{
    const int4* ip = (const int4*)(ids + (size_t)b * L);
    const int4* mp = (const int4*)(mask + (size_t)b * L);
    int id[L], m[L];
    #pragma unroll
    for (int i = 0; i < L / 4; ++i) {
        int4 ti = ip[i];
        id[4*i+0] = rfl(ti.x); id[4*i+1] = rfl(ti.y);
        id[4*i+2] = rfl(ti.z); id[4*i+3] = rfl(ti.w);
        int4 tm = mp[i];
        m[4*i+0] = rfl(tm.x); m[4*i+1] = rfl(tm.y);
        m[4*i+2] = rfl(tm.z); m[4*i+3] = rfl(tm.w);
    }
    int cnt = 0;
    #pragma unroll
    for (int l = 0; l < L; ++l) cnt += (m[l] ? 1 : 0);

    // unconditional gathers; masked slots read row 0 (L1-hot), corrected below
    float v[L];
    #pragma unroll
    for (int l = 0; l < L; ++l) {
        int sid = m[l] ? id[l] : 0;          // scalar select (SALU)
        v[l] = __bfloat162float(wt[(size_t)sid * RP + doff]);
    }
    float s0 = 0.f, s1 = 0.f, s2 = 0.f, s3 = 0.f;
    #pragma unroll
    for (int l = 0; l < L; l += 4) {
        s0 += v[l]; s1 += v[l+1]; s2 += v[l+2]; s3 += v[l+3];
    }
    float acc = (s0 + s1) + (s2 + s3);
    float v0 = __bfloat162float(wt[doff]);
    acc -= (float)(L - cnt) * v0;            // exact: masked slots loaded row 0
    return acc / (float)(cnt > 0 ? cnt : 1);
}

__global__ __launch_bounds__(256) void score_kernel(
    const __hip_bfloat16* __restrict__ wt,   // normalized word table [NW*RP]
    const __hip_bfloat16* __restrict__ et,   // normalized ent table
    const __hip_bfloat16* __restrict__ rt,   // normalized rel table
    const float* __restrict__ e_bias,
    const float* __restrict__ r_bias,
    const int* __restrict__ head,
    const int* __restrict__ relation,
    const int* __restrict__ tail,
    const int* __restrict__ head_w,
    const int* __restrict__ rel_w,
    const int* __restrict__ tail_w,
    const int* __restrict__ head_m,
    const int* __restrict__ rel_m,
    const int* __restrict__ tail_m,
    float* __restrict__ out,
    int B)
{
    int wid = (int)((blockIdx.x * (unsigned)blockDim.x + threadIdx.x) >> 6);
    int lane = (int)(threadIdx.x & 63u);
    if (wid >= B) return;
    int b = rfl(wid);

    int d = lane;
    int doff = (d < D) ? d : 0;   // inactive lanes read dim 0; zeroed before reduce

    int h = rfl(head[b]);
    int r = rfl(relation[b]);
    int t = rfl(tail[b]);

    float vh = __bfloat162float(et[(size_t)h * RP + doff]);
    float vr = __bfloat162float(rt[(size_t)r * RP + doff]);
    float vt = __bfloat162float(et[(size_t)t * RP + doff]);

    float ph = pool_bf16(wt, head_w, head_m, b, doff);
    float pr = pool_bf16(wt, rel_w,  rel_m,  b, doff);
    float pt = pool_bf16(wt, tail_w, tail_m, b, doff);

    float comb = (vh + ph) + (vr + pr) - (vt + pt);
    comb = (d < D) ? comb : 0.f;
    float nsc = sqrtf(wave_sum(comb * comb));

    float score = -nsc + e_bias[h] + e_bias[t] + r_bias[r];
    if (lane == 0) out[wid] = score;
}

// ---------- slow fallback (round-0 verified; used only if ws too small) ----------
__device__ __forceinline__ float word_pool_slow(const float* __restrict__ word_emb,
                                                const int* __restrict__ ids,
                                                const int* __restrict__ mask,
                                                int b, int d, bool act)
{
    float acc = 0.f;
    int cnt = 0;
    #pragma unroll
    for (int l = 0; l < L; ++l) {
        int m = mask[b * L + l];
        if (m) {
            int id = ids[b * L + l];
            float v = act ? word_emb[(size_t)id * D + d] : 0.f;
            float n = sqrtf(wave_sum(v * v));
            acc += v / fmaxf(n, NORM_EPS);
            cnt += 1;
        }
    }
    return acc / (float)(cnt > 0 ? cnt : 1);
}

__global__ __launch_bounds__(256) void transe_score_slow_kernel(
    const float* __restrict__ ent_emb, const float* __restrict__ rel_emb,
    const float* __restrict__ word_emb, const float* __restrict__ e_bias,
    const float* __restrict__ r_bias,
    const int* __restrict__ head, const int* __restrict__ relation,
    const int* __restrict__ tail,
    const int* __restrict__ head_w, const int* __restrict__ rel_w,
    const int* __restrict__ tail_w,
    const int* __restrict__ head_m, const int* __restrict__ rel_m,
    const int* __restrict__ tail_m,
    float* __restrict__ out, int B)
{
    int wid = (int)((blockIdx.x * (unsigned)blockDim.x + threadIdx.x) >> 6);
    int lane = (int)(threadIdx.x & 63u);
    if (wid >= B) return;
    int d = lane;
    bool act = d < D;

    int h = head[wid], r = relation[wid], t = tail[wid];

    float vh = act ? ent_emb[(size_t)h * D + d] : 0.f;
    float vr = act ? rel_emb[(size_t)r * D + d] : 0.f;
    float vt = act ? ent_emb[(size_t)t * D + d] : 0.f;
    vh /= fmaxf(sqrtf(wave_sum(vh * vh)), NORM_EPS);
    vr /= fmaxf(sqrtf(wave_sum(vr * vr)), NORM_EPS);
    vt /= fmaxf(sqrtf(wave_sum(vt * vt)), NORM_EPS);

    float ph = word_pool_slow(word_emb, head_w, head_m, wid, d, act);
    float pr = word_pool_slow(word_emb, rel_w,  rel_m,  wid, d, act);
    float pt = word_pool_slow(word_emb, tail_w, tail_m, wid, d, act);

    float comb = (vh + ph) + (vr + pr) - (vt + pt);
    float nsc = sqrtf(wave_sum(comb * comb));
    float score = -nsc + e_bias[h] + e_bias[t] + r_bias[r];
    if (lane == 0) out[wid] = score;
}

extern "C" void kernel_launch(void* const* d_in, const int* in_sizes, int n_in,
                              void* d_out, int out_size, void* d_ws, size_t ws_size,
                              hipStream_t stream) {
    const float* ent_emb  = (const float*)d_in[0];
    const float* rel_emb  = (const float*)d_in[1];
    const float* word_emb = (const float*)d_in[2];
    const float* e_bias   = (const float*)d_in[3];
    const float* r_bias   = (const float*)d_in[4];
    const int*   head     = (const int*)d_in[5];
    const int*   relation = (const int*)d_in[6];
    const int*   tail     = (const int*)d_in[7];
    const int*   head_w   = (const int*)d_in[8];
    const int*   rel_w    = (const int*)d_in[9];
    const int*   tail_w   = (const int*)d_in[10];
    const int*   head_m   = (const int*)d_in[11];
    const int*   rel_m    = (const int*)d_in[12];
    const int*   tail_m   = (const int*)d_in[13];
    float* out = (float*)d_out;

    int B  = in_sizes[5];
    int NE = in_sizes[0] / D;   // 500000
    int NR = in_sizes[1] / D;   // 1000
    int NW = in_sizes[2] / D;   // 100000

    int wpb = 256 / 64;  // waves per block (score kernel)

    size_t need_A = (size_t)(NW + NE + NR) * RP * sizeof(__hip_bfloat16);  // ~77 MB

    if (ws_size >= need_A) {
        __hip_bfloat16* wt = (__hip_bfloat16*)d_ws;
        __hip_bfloat16* et = wt + (size_t)NW * RP;
        __hip_bfloat16* rt = et + (size_t)NE * RP;

        norm_bf16_fast_kernel<<<(NW + 255) / 256, 256, 0, stream>>>(word_emb, wt, NW);
        norm_bf16_fast_kernel<<<(NE + 255) / 256, 256, 0, stream>>>(ent_emb, et, NE);
        norm_bf16_fast_kernel<<<(NR + 255) / 256, 256, 0, stream>>>(rel_emb, rt, NR);

        score_kernel<<<(B + wpb - 1) / wpb, 256, 0, stream>>>(
            wt, et, rt,
            e_bias, r_bias, head, relation, tail,
            head_w, rel_w, tail_w, head_m, rel_m, tail_m, out, B);
    } else {
        transe_score_slow_kernel<<<(B + wpb - 1) / wpb, 256, 0, stream>>>(
            ent_emb, rel_emb, word_emb, e_bias, r_bias,
            head, relation, tail,
            head_w, rel_w, tail_w, head_m, rel_m, tail_m, out, B);
    }
}

// Round 7
// 124.161 us; speedup vs baseline: 3.5822x; 1.1976x over previous
//
#include <hip/hip_runtime.h>
#include <hip/hip_bf16.h>

#define NORM_EPS 1e-12f
#define D 60
#define RP 64    // padded row length (elements) -> 128 B rows, line-aligned
#define L 24
#define SSTR 28  // sanitized list stride in dwords (24 sids + invcnt + nmask + 2 pad)

__device__ __forceinline__ float wave_sum(float v) {
    #pragma unroll
    for (int off = 32; off >= 1; off >>= 1)
        v += __shfl_xor(v, off, 64);
    return v;
}

__device__ __forceinline__ int rfl(int x) { return __builtin_amdgcn_readfirstlane(x); }

__device__ __forceinline__ float bf2f(unsigned short u) {
    unsigned x = (unsigned)u << 16;
    float f;
    __builtin_memcpy(&f, &x, 4);
    return f;
}

__device__ __forceinline__ unsigned pack_bf16(float a, float b) {
    __hip_bfloat16 lo = __float2bfloat16(a);   // RNE
    __hip_bfloat16 hi = __float2bfloat16(b);
    unsigned short ul, uh;
    __builtin_memcpy(&ul, &lo, 2);
    __builtin_memcpy(&uh, &hi, 2);
    return (unsigned)ul | ((unsigned)uh << 16);
}

// ---------- precompute: L2-normalized bf16 table, thread-per-row ----------
__global__ __launch_bounds__(256) void norm_bf16_fast_kernel(
    const float* __restrict__ emb, __hip_bfloat16* __restrict__ outw, int N)
{
    int row = (int)(blockIdx.x * blockDim.x + threadIdx.x);
    if (row >= N) return;

    const float4* src = (const float4*)(emb + (size_t)row * D);
    float4 v[15];
    #pragma unroll
    for (int i = 0; i < 15; ++i) v[i] = src[i];

    float ss = 0.f;
    #pragma unroll
    for (int i = 0; i < 15; ++i)
        ss += v[i].x * v[i].x + v[i].y * v[i].y + v[i].z * v[i].z + v[i].w * v[i].w;
    float inv = 1.f / fmaxf(sqrtf(ss), NORM_EPS);

    float f[60];
    #pragma unroll
    for (int i = 0; i < 15; ++i) {
        f[4*i+0] = v[i].x * inv; f[4*i+1] = v[i].y * inv;
        f[4*i+2] = v[i].z * inv; f[4*i+3] = v[i].w * inv;
    }
    unsigned w[32];
    #pragma unroll
    for (int i = 0; i < 30; ++i) w[i] = pack_bf16(f[2*i], f[2*i+1]);
    w[30] = 0u; w[31] = 0u;

    uint4* dst = (uint4*)(outw + (size_t)row * RP);
    #pragma unroll
    for (int j = 0; j < 8; ++j)
        dst[j] = make_uint4(w[4*j+0], w[4*j+1], w[4*j+2], w[4*j+3]);
}

// ---------- precompute: sanitize id lists (mask folded in) ----------
__global__ __launch_bounds__(256) void sanitize_kernel(
    const int* __restrict__ hw, const int* __restrict__ rw, const int* __restrict__ tw,
    const int* __restrict__ hm, const int* __restrict__ rm, const int* __restrict__ tm,
    int* __restrict__ sids, int B)
{
    int b = (int)(blockIdx.x * blockDim.x + threadIdx.x);
    if (b >= B) return;

    const int* idp[3] = { hw, rw, tw };
    const int* mkp[3] = { hm, rm, tm };
    int* o = sids + (size_t)b * (3 * SSTR);

    #pragma unroll
    for (int s = 0; s < 3; ++s) {
        const int4* ip = (const int4*)(idp[s] + (size_t)b * L);
        const int4* mp = (const int4*)(mkp[s] + (size_t)b * L);
        int cnt = 0;
        int4* ov = (int4*)o;
        #pragma unroll
        for (int i = 0; i < L / 4; ++i) {
            int4 ti = ip[i];
            int4 tm4 = mp[i];
            int4 so;
            so.x = tm4.x ? ti.x : 0; cnt += (tm4.x ? 1 : 0);
            so.y = tm4.y ? ti.y : 0; cnt += (tm4.y ? 1 : 0);
            so.z = tm4.z ? ti.z : 0; cnt += (tm4.z ? 1 : 0);
            so.w = tm4.w ? ti.w : 0; cnt += (tm4.w ? 1 : 0);
            ov[i] = so;
        }
        float invc = 1.f / (float)(cnt > 0 ? cnt : 1);
        float nm   = (float)(L - cnt);
        ov[6] = make_int4(__float_as_int(invc), __float_as_int(nm), 0, 0);
        o += SSTR;
    }
}

// ---------- score: flat-issue 75 gathers per item, deep MLP ----------
__global__ __launch_bounds__(256) void score_kernel(
    const __hip_bfloat16* __restrict__ wt,
    const __hip_bfloat16* __restrict__ et,
    const __hip_bfloat16* __restrict__ rt,
    const int* __restrict__ sids,
    const float* __restrict__ e_bias,
    const float* __restrict__ r_bias,
    const int* __restrict__ head,
    const int* __restrict__ relation,
    const int* __restrict__ tail,
    float* __restrict__ out,
    int B)
{
    int wid = (int)((blockIdx.x * (unsigned)blockDim.x + threadIdx.x) >> 6);
    int lane = (int)(threadIdx.x & 63u);
    if (wid >= B) return;
    int b = rfl(wid);

    int d = lane;
    unsigned doff2 = (unsigned)(((d < D) ? d : 0) * 2);   // byte offset within row

    // uniform index loads (same value in all lanes)
    int h = head[b];
    int r = relation[b];
    int t = tail[b];

    const char* wtb = (const char*)wt;
    const char* etb = (const char*)et;
    const char* rtb = (const char*)rt;

    // all sanitized list data for this item: 84 dwords = 21 int4 (uniform addr)
    const int4* sb = (const int4*)(sids + (size_t)b * (3 * SSTR));
    int4 q[21];
    #pragma unroll
    for (int i = 0; i < 21; ++i) q[i] = sb[i];

    // compute all 72 gather byte-offsets (1 v_lshl_add each)
    unsigned off[72];
    #pragma unroll
    for (int s = 0; s < 3; ++s) {
        #pragma unroll
        for (int i = 0; i < 6; ++i) {
            int4 ti = q[s * 7 + i];
            int base = s * 24 + 4 * i;
            off[base + 0] = ((unsigned)ti.x << 7) + doff2;
            off[base + 1] = ((unsigned)ti.y << 7) + doff2;
            off[base + 2] = ((unsigned)ti.z << 7) + doff2;
            off[base + 3] = ((unsigned)ti.w << 7) + doff2;
        }
    }

    // issue ALL gathers flat: 72 word rows + row0 + 3 entity rows
    unsigned short raw[72];
    #pragma unroll
    for (int j = 0; j < 72; ++j)
        raw[j] = *(const unsigned short*)(wtb + off[j]);
    unsigned short raw0 = *(const unsigned short*)(wtb + doff2);
    unsigned short rawh = *(const unsigned short*)(etb + (((unsigned)h << 7) + doff2));
    unsigned short rawr = *(const unsigned short*)(rtb + (((unsigned)r << 7) + doff2));
    unsigned short rawt = *(const unsigned short*)(etb + (((unsigned)t << 7) + doff2));

    float v0 = bf2f(raw0);
    float pool[3];
    #pragma unroll
    for (int s = 0; s < 3; ++s) {
        float s0 = 0.f, s1 = 0.f, s2 = 0.f, s3 = 0.f;
        #pragma unroll
        for (int l = 0; l < L; l += 4) {
            s0 += bf2f(raw[s * 24 + l + 0]);
            s1 += bf2f(raw[s * 24 + l + 1]);
            s2 += bf2f(raw[s * 24 + l + 2]);
            s3 += bf2f(raw[s * 24 + l + 3]);
        }
        float acc = (s0 + s1) + (s2 + s3);
        float invc = __int_as_float(q[s * 7 + 6].x);
        float nm   = __int_as_float(q[s * 7 + 6].y);
        pool[s] = (acc - nm * v0) * invc;
    }

    float vh = bf2f(rawh);
    float vr = bf2f(rawr);
    float vt = bf2f(rawt);

    float comb = (vh + pool[0]) + (vr + pool[1]) - (vt + pool[2]);
    comb = (d < D) ? comb : 0.f;
    float nsc = sqrtf(wave_sum(comb * comb));

    float score = -nsc + e_bias[h] + e_bias[t] + r_bias[r];
    if (lane == 0) out[wid] = score;
}

// ---------- round-5 verified path (tables only, rfl scalarization) ----------
__device__ __forceinline__ float pool_bf16(const __hip_bfloat16* __restrict__ wt,
                                           const int* __restrict__ ids,
                                           const int* __restrict__ mask,
                                           int b, int doff)
{
    const int4* ip = (const int4*)(ids + (size_t)b * L);
    const int4* mp = (const int4*)(mask + (size_t)b * L);
    int id[L], m[L];
    #pragma unroll
    for (int i = 0; i < L / 4; ++i) {
        int4 ti = ip[i];
        id[4*i+0] = rfl(ti.x); id[4*i+1] = rfl(ti.y);
        id[4*i+2] = rfl(ti.z); id[4*i+3] = rfl(ti.w);
        int4 tm = mp[i];
        m[4*i+0] = rfl(tm.x); m[4*i+1] = rfl(tm.y);
        m[4*i+2] = rfl(tm.z); m[4*i+3] = rfl(tm.w);
    }
    int cnt = 0;
    #pragma unroll
    for (int l = 0; l < L; ++l) cnt += (m[l] ? 1 : 0);
    float v[L];
    #pragma unroll
    for (int l = 0; l < L; ++l) {
        int sid = m[l] ? id[l] : 0;
        v[l] = __bfloat162float(wt[(size_t)sid * RP + doff]);
    }
    float s0 = 0.f, s1 = 0.f, s2 = 0.f, s3 = 0.f;
    #pragma unroll
    for (int l = 0; l < L; l += 4) {
        s0 += v[l]; s1 += v[l+1]; s2 += v[l+2]; s3 += v[l+3];
    }
    float acc = (s0 + s1) + (s2 + s3);
    float v0 = __bfloat162float(wt[doff]);
    acc -= (float)(L - cnt) * v0;
    return acc / (float)(cnt > 0 ? cnt : 1);
}

__global__ __launch_bounds__(256) void score_kernel_r5(
    const __hip_bfloat16* __restrict__ wt,
    const __hip_bfloat16* __restrict__ et,
    const __hip_bfloat16* __restrict__ rt,
    const float* __restrict__ e_bias,
    const float* __restrict__ r_bias,
    const int* __restrict__ head,
    const int* __restrict__ relation,
    const int* __restrict__ tail,
    const int* __restrict__ head_w,
    const int* __restrict__ rel_w,
    const int* __restrict__ tail_w,
    const int* __restrict__ head_m,
    const int* __restrict__ rel_m,
    const int* __restrict__ tail_m,
    float* __restrict__ out,
    int B)
{
    int wid = (int)((blockIdx.x * (unsigned)blockDim.x + threadIdx.x) >> 6);
    int lane = (int)(threadIdx.x & 63u);
    if (wid >= B) return;
    int b = rfl(wid);
    int d = lane;
    int doff = (d < D) ? d : 0;

    int h = rfl(head[b]);
    int r = rfl(relation[b]);
    int t = rfl(tail[b]);

    float vh = __bfloat162float(et[(size_t)h * RP + doff]);
    float vr = __bfloat162float(rt[(size_t)r * RP + doff]);
    float vt = __bfloat162float(et[(size_t)t * RP + doff]);

    float ph = pool_bf16(wt, head_w, head_m, b, doff);
    float pr = pool_bf16(wt, rel_w,  rel_m,  b, doff);
    float pt = pool_bf16(wt, tail_w, tail_m, b, doff);

    float comb = (vh + ph) + (vr + pr) - (vt + pt);
    comb = (d < D) ? comb : 0.f;
    float nsc = sqrtf(wave_sum(comb * comb));
    float score = -nsc + e_bias[h] + e_bias[t] + r_bias[r];
    if (lane == 0) out[wid] = score;
}

// ---------- slow fallback (round-0 verified) ----------
__device__ __forceinline__ float word_pool_slow(const float* __restrict__ word_emb,
                                                const int* __restrict__ ids,
                                                const int* __restrict__ mask,
                                                int b, int d, bool act)
{
    float acc = 0.f;
    int cnt = 0;
    #pragma unroll
    for (int l = 0; l < L; ++l) {
        int m = mask[b * L + l];
        if (m) {
            int id = ids[b * L + l];
            float v = act ? word_emb[(size_t)id * D + d] : 0.f;
            float n = sqrtf(wave_sum(v * v));
            acc += v / fmaxf(n, NORM_EPS);
            cnt += 1;
        }
    }
    return acc / (float)(cnt > 0 ? cnt : 1);
}

__global__ __launch_bounds__(256) void transe_score_slow_kernel(
    const float* __restrict__ ent_emb, const float* __restrict__ rel_emb,
    const float* __restrict__ word_emb, const float* __restrict__ e_bias,
    const float* __restrict__ r_bias,
    const int* __restrict__ head, const int* __restrict__ relation,
    const int* __restrict__ tail,
    const int* __restrict__ head_w, const int* __restrict__ rel_w,
    const int* __restrict__ tail_w,
    const int* __restrict__ head_m, const int* __restrict__ rel_m,
    const int* __restrict__ tail_m,
    float* __restrict__ out, int B)
{
    int wid = (int)((blockIdx.x * (unsigned)blockDim.x + threadIdx.x) >> 6);
    int lane = (int)(threadIdx.x & 63u);
    if (wid >= B) return;
    int d = lane;
    bool act = d < D;

    int h = head[wid], r = relation[wid], t = tail[wid];

    float vh = act ? ent_emb[(size_t)h * D + d] : 0.f;
    float vr = act ? rel_emb[(size_t)r * D + d] : 0.f;
    float vt = act ? ent_emb[(size_t)t * D + d] : 0.f;
    vh /= fmaxf(sqrtf(wave_sum(vh * vh)), NORM_EPS);
    vr /= fmaxf(sqrtf(wave_sum(vr * vr)), NORM_EPS);
    vt /= fmaxf(sqrtf(wave_sum(vt * vt)), NORM_EPS);

    float ph = word_pool_slow(word_emb, head_w, head_m, wid, d, act);
    float pr = word_pool_slow(word_emb, rel_w,  rel_m,  wid, d, act);
    float pt = word_pool_slow(word_emb, tail_w, tail_m, wid, d, act);

    float comb = (vh + ph) + (vr + pr) - (vt + pt);
    float nsc = sqrtf(wave_sum(comb * comb));
    float score = -nsc + e_bias[h] + e_bias[t] + r_bias[r];
    if (lane == 0) out[wid] = score;
}

extern "C" void kernel_launch(void* const* d_in, const int* in_sizes, int n_in,
                              void* d_out, int out_size, void* d_ws, size_t ws_size,
                              hipStream_t stream) {
    const float* ent_emb  = (const float*)d_in[0];
    const float* rel_emb  = (const float*)d_in[1];
    const float* word_emb = (const float*)d_in[2];
    const float* e_bias   = (const float*)d_in[3];
    const float* r_bias   = (const float*)d_in[4];
    const int*   head     = (const int*)d_in[5];
    const int*   relation = (const int*)d_in[6];
    const int*   tail     = (const int*)d_in[7];
    const int*   head_w   = (const int*)d_in[8];
    const int*   rel_w    = (const int*)d_in[9];
    const int*   tail_w   = (const int*)d_in[10];
    const int*   head_m   = (const int*)d_in[11];
    const int*   rel_m    = (const int*)d_in[12];
    const int*   tail_m   = (const int*)d_in[13];
    float* out = (float*)d_out;

    int B  = in_sizes[5];
    int NE = in_sizes[0] / D;   // 500000
    int NR = in_sizes[1] / D;   // 1000
    int NW = in_sizes[2] / D;   // 100000

    int wpb = 256 / 64;  // waves per block (score kernel)

    size_t tab_elems = (size_t)(NW + NE + NR) * RP;
    size_t need_tab  = tab_elems * sizeof(__hip_bfloat16);                 // ~77 MB
    size_t need_sid  = (size_t)B * 3 * SSTR * sizeof(int);                 // ~22 MB

    if (ws_size >= need_tab + need_sid) {
        __hip_bfloat16* wt = (__hip_bfloat16*)d_ws;
        __hip_bfloat16* et = wt + (size_t)NW * RP;
        __hip_bfloat16* rt = et + (size_t)NE * RP;
        int* sids = (int*)((char*)d_ws + need_tab);

        norm_bf16_fast_kernel<<<(NW + 255) / 256, 256, 0, stream>>>(word_emb, wt, NW);
        norm_bf16_fast_kernel<<<(NE + 255) / 256, 256, 0, stream>>>(ent_emb, et, NE);
        norm_bf16_fast_kernel<<<(NR + 255) / 256, 256, 0, stream>>>(rel_emb, rt, NR);
        sanitize_kernel<<<(B + 255) / 256, 256, 0, stream>>>(
            head_w, rel_w, tail_w, head_m, rel_m, tail_m, sids, B);

        score_kernel<<<(B + wpb - 1) / wpb, 256, 0, stream>>>(
            wt, et, rt, sids,
            e_bias, r_bias, head, relation, tail, out, B);
    } else if (ws_size >= need_tab) {
        __hip_bfloat16* wt = (__hip_bfloat16*)d_ws;
        __hip_bfloat16* et = wt + (size_t)NW * RP;
        __hip_bfloat16* rt = et + (size_t)NE * RP;

        norm_bf16_fast_kernel<<<(NW + 255) / 256, 256, 0, stream>>>(word_emb, wt, NW);
        norm_bf16_fast_kernel<<<(NE + 255) / 256, 256, 0, stream>>>(ent_emb, et, NE);
        norm_bf16_fast_kernel<<<(NR + 255) / 256, 256, 0, stream>>>(rel_emb, rt, NR);

        score_kernel_r5<<<(B + wpb - 1) / wpb, 256, 0, stream>>>(
            wt, et, rt,
            e_bias, r_bias, head, relation, tail,
            head_w, rel_w, tail_w, head_m, rel_m, tail_m, out, B);
    } else {
        transe_score_slow_kernel<<<(B + wpb - 1) / wpb, 256, 0, stream>>>(
            ent_emb, rel_emb, word_emb, e_bias, r_bias,
            head, relation, tail,
            head_w, rel_w, tail_w, head_m, rel_m, tail_m, out, B);
    }
}

// Round 8
// 92.414 us; speedup vs baseline: 4.8129x; 1.3435x over previous
//
#include <hip/hip_runtime.h>
#include <hip/hip_bf16.h>

#define NORM_EPS 1e-12f
#define D 60
#define RP 64     // padded row length (elements) -> 128 B rows, line-aligned
#define L 24
#define SSTR 28   // per-list dwords in blob (24 sids + invc + 3 pad)
#define ITEM_STRIDE 768   // per-item blob bytes (6 cache lines)
#define BIAS_OFF 336
#define ROWS_OFF 384

__device__ __forceinline__ float wave_sum(float v) {
    #pragma unroll
    for (int off = 32; off >= 1; off >>= 1)
        v += __shfl_xor(v, off, 64);
    return v;
}

__device__ __forceinline__ int rfl(int x) { return __builtin_amdgcn_readfirstlane(x); }

__device__ __forceinline__ float bf2f(unsigned short u) {
    unsigned x = (unsigned)u << 16;
    float f;
    __builtin_memcpy(&f, &x, 4);
    return f;
}

__device__ __forceinline__ unsigned pack_bf16(float a, float b) {
    __hip_bfloat16 lo = __float2bfloat16(a);   // RNE
    __hip_bfloat16 hi = __float2bfloat16(b);
    unsigned short ul, uh;
    __builtin_memcpy(&ul, &lo, 2);
    __builtin_memcpy(&uh, &hi, 2);
    return (unsigned)ul | ((unsigned)uh << 16);
}

// ---------- precompute: L2-normalized bf16 table, thread-per-row ----------
// zrow != 0: also write an all-zeros row at index N (grid must cover N+1)
__global__ __launch_bounds__(256) void norm_bf16_tab_kernel(
    const float* __restrict__ emb, __hip_bfloat16* __restrict__ outw, int N, int zrow)
{
    int row = (int)(blockIdx.x * blockDim.x + threadIdx.x);
    if (row >= N + zrow) return;

    uint4* dst = (uint4*)(outw + (size_t)row * RP);
    if (row == N) {  // zero row (only reachable when zrow==1)
        uint4 z = make_uint4(0u, 0u, 0u, 0u);
        #pragma unroll
        for (int j = 0; j < 8; ++j) dst[j] = z;
        return;
    }

    const float4* src = (const float4*)(emb + (size_t)row * D);
    float4 v[15];
    #pragma unroll
    for (int i = 0; i < 15; ++i) v[i] = src[i];

    float ss = 0.f;
    #pragma unroll
    for (int i = 0; i < 15; ++i)
        ss += v[i].x * v[i].x + v[i].y * v[i].y + v[i].z * v[i].z + v[i].w * v[i].w;
    float inv = 1.f / fmaxf(sqrtf(ss), NORM_EPS);

    float f[60];
    #pragma unroll
    for (int i = 0; i < 15; ++i) {
        f[4*i+0] = v[i].x * inv; f[4*i+1] = v[i].y * inv;
        f[4*i+2] = v[i].z * inv; f[4*i+3] = v[i].w * inv;
    }
    unsigned w[32];
    #pragma unroll
    for (int i = 0; i < 30; ++i) w[i] = pack_bf16(f[2*i], f[2*i+1]);
    w[30] = 0u; w[31] = 0u;

    #pragma unroll
    for (int j = 0; j < 8; ++j)
        dst[j] = make_uint4(w[4*j+0], w[4*j+1], w[4*j+2], w[4*j+3]);
}

// ---------- fused prep: sanitize lists + normalize h/r/t rows + bias ----------
__device__ __forceinline__ void write_norm_row(const float* __restrict__ src,
                                               char* __restrict__ dst)
{
    const float4* s4 = (const float4*)src;   // 240 B row, 16B-aligned
    float4 v[15];
    #pragma unroll
    for (int i = 0; i < 15; ++i) v[i] = s4[i];
    float ss = 0.f;
    #pragma unroll
    for (int i = 0; i < 15; ++i)
        ss += v[i].x * v[i].x + v[i].y * v[i].y + v[i].z * v[i].z + v[i].w * v[i].w;
    float inv = 1.f / fmaxf(sqrtf(ss), NORM_EPS);
    float f[60];
    #pragma unroll
    for (int i = 0; i < 15; ++i) {
        f[4*i+0] = v[i].x * inv; f[4*i+1] = v[i].y * inv;
        f[4*i+2] = v[i].z * inv; f[4*i+3] = v[i].w * inv;
    }
    unsigned w[32];
    #pragma unroll
    for (int i = 0; i < 30; ++i) w[i] = pack_bf16(f[2*i], f[2*i+1]);
    w[30] = 0u; w[31] = 0u;
    uint4* d4 = (uint4*)dst;
    #pragma unroll
    for (int j = 0; j < 8; ++j)
        d4[j] = make_uint4(w[4*j+0], w[4*j+1], w[4*j+2], w[4*j+3]);
}

__global__ __launch_bounds__(256) void prep_kernel(
    const float* __restrict__ ent_emb, const float* __restrict__ rel_emb,
    const float* __restrict__ e_bias, const float* __restrict__ r_bias,
    const int* __restrict__ head, const int* __restrict__ relation,
    const int* __restrict__ tail,
    const int* __restrict__ hw, const int* __restrict__ rw, const int* __restrict__ tw,
    const int* __restrict__ hm, const int* __restrict__ rm, const int* __restrict__ tm,
    char* __restrict__ blob, int B, int NW)
{
    int b = (int)(blockIdx.x * blockDim.x + threadIdx.x);
    if (b >= B) return;

    char* ob = blob + (size_t)b * ITEM_STRIDE;

    // --- sanitized id lists: masked slots -> zero row (index NW) ---
    const int* idp[3] = { hw, rw, tw };
    const int* mkp[3] = { hm, rm, tm };
    int* o = (int*)ob;
    #pragma unroll
    for (int s = 0; s < 3; ++s) {
        const int4* ip = (const int4*)(idp[s] + (size_t)b * L);
        const int4* mp = (const int4*)(mkp[s] + (size_t)b * L);
        int cnt = 0;
        int4* ov = (int4*)o;
        #pragma unroll
        for (int i = 0; i < L / 4; ++i) {
            int4 ti = ip[i];
            int4 tm4 = mp[i];
            int4 so;
            so.x = tm4.x ? ti.x : NW; cnt += (tm4.x ? 1 : 0);
            so.y = tm4.y ? ti.y : NW; cnt += (tm4.y ? 1 : 0);
            so.z = tm4.z ? ti.z : NW; cnt += (tm4.z ? 1 : 0);
            so.w = tm4.w ? ti.w : NW; cnt += (tm4.w ? 1 : 0);
            ov[i] = so;
        }
        float invc = 1.f / (float)(cnt > 0 ? cnt : 1);
        ov[6] = make_int4(__float_as_int(invc), 0, 0, 0);
        o += SSTR;
    }

    // --- bias sum + normalized h/r/t rows ---
    int h = head[b];
    int r = relation[b];
    int t = tail[b];
    float bias = e_bias[h] + e_bias[t] + r_bias[r];
    *(float*)(ob + BIAS_OFF) = bias;

    write_norm_row(ent_emb + (size_t)h * D, ob + ROWS_OFF);
    write_norm_row(rel_emb + (size_t)r * D, ob + ROWS_OFF + 128);
    write_norm_row(ent_emb + (size_t)t * D, ob + ROWS_OFF + 256);
}

// ---------- score: flat-issue 72 word gathers + 6-line uniform blob ----------
__global__ __launch_bounds__(256) void score_kernel_v8(
    const __hip_bfloat16* __restrict__ wt,
    const char* __restrict__ blob,
    float* __restrict__ out,
    int B)
{
    int wid = (int)((blockIdx.x * (unsigned)blockDim.x + threadIdx.x) >> 6);
    int lane = (int)(threadIdx.x & 63u);
    if (wid >= B) return;
    int b = rfl(wid);

    int d = lane;
    unsigned doff2 = (unsigned)(((d < D) ? d : 0) * 2);   // byte offset within row

    const char* ob = blob + (size_t)b * ITEM_STRIDE;
    const char* wtb = (const char*)wt;

    // sanitized lists: 84 dwords = 21 int4 (uniform addr)
    const int4* sb = (const int4*)ob;
    int4 q[21];
    #pragma unroll
    for (int i = 0; i < 21; ++i) q[i] = sb[i];

    // 72 gather byte-offsets
    unsigned off[72];
    #pragma unroll
    for (int s = 0; s < 3; ++s) {
        #pragma unroll
        for (int i = 0; i < 6; ++i) {
            int4 ti = q[s * 7 + i];
            int base = s * 24 + 4 * i;
            off[base + 0] = ((unsigned)ti.x << 7) + doff2;
            off[base + 1] = ((unsigned)ti.y << 7) + doff2;
            off[base + 2] = ((unsigned)ti.z << 7) + doff2;
            off[base + 3] = ((unsigned)ti.w << 7) + doff2;
        }
    }

    // issue all gathers flat: 72 word rows + 3 blob rows + bias
    unsigned short raw[72];
    #pragma unroll
    for (int j = 0; j < 72; ++j)
        raw[j] = *(const unsigned short*)(wtb + off[j]);
    unsigned short rawh = *(const unsigned short*)(ob + ROWS_OFF + doff2);
    unsigned short rawr = *(const unsigned short*)(ob + ROWS_OFF + 128 + doff2);
    unsigned short rawt = *(const unsigned short*)(ob + ROWS_OFF + 256 + doff2);
    float bias = *(const float*)(ob + BIAS_OFF);

    float pool[3];
    #pragma unroll
    for (int s = 0; s < 3; ++s) {
        float s0 = 0.f, s1 = 0.f, s2 = 0.f, s3 = 0.f;
        #pragma unroll
        for (int l = 0; l < L; l += 4) {
            s0 += bf2f(raw[s * 24 + l + 0]);
            s1 += bf2f(raw[s * 24 + l + 1]);
            s2 += bf2f(raw[s * 24 + l + 2]);
            s3 += bf2f(raw[s * 24 + l + 3]);
        }
        float acc = (s0 + s1) + (s2 + s3);
        pool[s] = acc * __int_as_float(q[s * 7 + 6].x);
    }

    float vh = bf2f(rawh);
    float vr = bf2f(rawr);
    float vt = bf2f(rawt);

    float comb = (vh + pool[0]) + (vr + pool[1]) - (vt + pool[2]);
    comb = (d < D) ? comb : 0.f;
    float nsc = sqrtf(wave_sum(comb * comb));

    float score = -nsc + bias;
    if (lane == 0) out[wid] = score;
}

// ---------- slow fallback (round-0 verified) ----------
__device__ __forceinline__ float word_pool_slow(const float* __restrict__ word_emb,
                                                const int* __restrict__ ids,
                                                const int* __restrict__ mask,
                                                int b, int d, bool act)
{
    float acc = 0.f;
    int cnt = 0;
    #pragma unroll
    for (int l = 0; l < L; ++l) {
        int m = mask[b * L + l];
        if (m) {
            int id = ids[b * L + l];
            float v = act ? word_emb[(size_t)id * D + d] : 0.f;
            float n = sqrtf(wave_sum(v * v));
            acc += v / fmaxf(n, NORM_EPS);
            cnt += 1;
        }
    }
    return acc / (float)(cnt > 0 ? cnt : 1);
}

__global__ __launch_bounds__(256) void transe_score_slow_kernel(
    const float* __restrict__ ent_emb, const float* __restrict__ rel_emb,
    const float* __restrict__ word_emb, const float* __restrict__ e_bias,
    const float* __restrict__ r_bias,
    const int* __restrict__ head, const int* __restrict__ relation,
    const int* __restrict__ tail,
    const int* __restrict__ head_w, const int* __restrict__ rel_w,
    const int* __restrict__ tail_w,
    const int* __restrict__ head_m, const int* __restrict__ rel_m,
    const int* __restrict__ tail_m,
    float* __restrict__ out, int B)
{
    int wid = (int)((blockIdx.x * (unsigned)blockDim.x + threadIdx.x) >> 6);
    int lane = (int)(threadIdx.x & 63u);
    if (wid >= B) return;
    int d = lane;
    bool act = d < D;

    int h = head[wid], r = relation[wid], t = tail[wid];

    float vh = act ? ent_emb[(size_t)h * D + d] : 0.f;
    float vr = act ? rel_emb[(size_t)r * D + d] : 0.f;
    float vt = act ? ent_emb[(size_t)t * D + d] : 0.f;
    vh /= fmaxf(sqrtf(wave_sum(vh * vh)), NORM_EPS);
    vr /= fmaxf(sqrtf(wave_sum(vr * vr)), NORM_EPS);
    vt /= fmaxf(sqrtf(wave_sum(vt * vt)), NORM_EPS);

    float ph = word_pool_slow(word_emb, head_w, head_m, wid, d, act);
    float pr = word_pool_slow(word_emb, rel_w,  rel_m,  wid, d, act);
    float pt = word_pool_slow(word_emb, tail_w, tail_m, wid, d, act);

    float comb = (vh + ph) + (vr + pr) - (vt + pt);
    float nsc = sqrtf(wave_sum(comb * comb));
    float score = -nsc + e_bias[h] + e_bias[t] + r_bias[r];
    if (lane == 0) out[wid] = score;
}

extern "C" void kernel_launch(void* const* d_in, const int* in_sizes, int n_in,
                              void* d_out, int out_size, void* d_ws, size_t ws_size,
                              hipStream_t stream) {
    const float* ent_emb  = (const float*)d_in[0];
    const float* rel_emb  = (const float*)d_in[1];
    const float* word_emb = (const float*)d_in[2];
    const float* e_bias   = (const float*)d_in[3];
    const float* r_bias   = (const float*)d_in[4];
    const int*   head     = (const int*)d_in[5];
    const int*   relation = (const int*)d_in[6];
    const int*   tail     = (const int*)d_in[7];
    const int*   head_w   = (const int*)d_in[8];
    const int*   rel_w    = (const int*)d_in[9];
    const int*   tail_w   = (const int*)d_in[10];
    const int*   head_m   = (const int*)d_in[11];
    const int*   rel_m    = (const int*)d_in[12];
    const int*   tail_m   = (const int*)d_in[13];
    float* out = (float*)d_out;

    int B  = in_sizes[5];
    int NE = in_sizes[0] / D;   // 500000
    int NR = in_sizes[1] / D;   // 1000
    int NW = in_sizes[2] / D;   // 100000
    (void)NE; (void)NR;

    int wpb = 256 / 64;  // waves per block (score kernel)

    size_t wt_bytes   = (size_t)(NW + 1) * RP * sizeof(__hip_bfloat16);  // ~12.8 MB
    size_t blob_bytes = (size_t)B * ITEM_STRIDE;                         // ~50 MB
    size_t need = wt_bytes + blob_bytes;

    if (ws_size >= need) {
        __hip_bfloat16* wt = (__hip_bfloat16*)d_ws;
        char* blob = (char*)d_ws + wt_bytes;

        norm_bf16_tab_kernel<<<(NW + 1 + 255) / 256, 256, 0, stream>>>(word_emb, wt, NW, 1);
        prep_kernel<<<(B + 255) / 256, 256, 0, stream>>>(
            ent_emb, rel_emb, e_bias, r_bias,
            head, relation, tail,
            head_w, rel_w, tail_w, head_m, rel_m, tail_m,
            blob, B, NW);

        score_kernel_v8<<<(B + wpb - 1) / wpb, 256, 0, stream>>>(
            wt, blob, out, B);
    } else {
        transe_score_slow_kernel<<<(B + wpb - 1) / wpb, 256, 0, stream>>>(
            ent_emb, rel_emb, word_emb, e_bias, r_bias,
            head, relation, tail,
            head_w, rel_w, tail_w, head_m, rel_m, tail_m, out, B);
    }
}